// Round 5
// baseline (198.639 us; speedup 1.0000x reference)
//
#include <hip/hip_runtime.h>

// ClusterNet fully fused: Q = rownorm(1/(1+dist(z,C))), P = rownorm(Q^2/colsum(Q))
// z: 8192x256 fp32, C: 64x256 fp32. out = [Q (8192x64) | P (8192x64)] fp32.
// dist^2 = ||z||^2 + ||c||^2 - 2 z.c
//
// Single kernel, 512 blocks x 512 threads. Device-wide sync via flags in ws:
// ws is re-poisoned to 0xAA before every launch, so MAGIC != initial value and
// no separate zeroing pass is needed. Co-residency guaranteed: launch_bounds
// (512,4) -> <=128 VGPR -> 2 blocks/CU x 256 CU = 512 = grid (LDS 38KB x2 <160KB).

#define M  8192
#define NC 64
#define H  256
#define BM 16
#define NBLK 512
#define MAGIC 0x13579BDFu

// ws layout (32-bit word index):
//   [0, 32768)       float  colsum partials [512][64]
//   [32768, 33280)   uint   arrival flags   [512]
//   [33344, 33352)   uint   ready flags     [8]
//   [33408, 33472)   float  invcs           [64]

__global__ __launch_bounds__(512, 4) void k_fused(
    const float* __restrict__ Z, const float* __restrict__ C,
    float* __restrict__ out, float* __restrict__ wsf)
{
    __shared__ float pd[8][BM][NC];   // per-wave dot partials (32 KB)
    __shared__ float ncp[8][NC];      // per-wave ||c||^2 partials
    __shared__ float nzs[BM];         // row norms
    __shared__ float csum[8][NC];     // per-wave colsum partials
    __shared__ float red[NBLK];       // reducer scratch
    __shared__ float invl[NC];        // broadcast 1/colsum

    unsigned int* wsu = (unsigned int*)wsf;
    float* partials      = wsf;
    unsigned int* aflag  = wsu + 32768;
    unsigned int* rflag  = wsu + 33344;
    float* invg          = wsf + 33408;

    const int t    = threadIdx.x;
    const int lane = t & 63;
    const int wid  = __builtin_amdgcn_readfirstlane(t >> 6);  // wave-uniform
    const int bid  = blockIdx.x;
    const int row0 = bid * BM;

    // ---- row norms ||z_r||^2: 32 threads per row ----
    {
        const int r  = t >> 5;       // 0..15
        const int sg = t & 31;
        const float4* zr = (const float4*)(Z + (size_t)(row0 + r) * H);
        float s = 0.f;
        #pragma unroll
        for (int i = 0; i < 2; ++i) {
            float4 v = zr[sg * 2 + i];
            s += v.x * v.x + v.y * v.y + v.z * v.z + v.w * v.w;
        }
        s += __shfl_xor(s, 1);
        s += __shfl_xor(s, 2);
        s += __shfl_xor(s, 4);
        s += __shfl_xor(s, 8);
        s += __shfl_xor(s, 16);
        if (sg == 0) nzs[r] = s;
    }

    // ---- centroid k-eighth -> 32 VGPRs (lane = cluster) ----
    float4 c4[8];
    {
        const float4* cp = (const float4*)(C + (size_t)lane * H + wid * 32);
        #pragma unroll
        for (int i = 0; i < 8; ++i) c4[i] = cp[i];
    }
    {
        float s = 0.f;
        #pragma unroll
        for (int i = 0; i < 8; ++i)
            s += c4[i].x * c4[i].x + c4[i].y * c4[i].y + c4[i].z * c4[i].z + c4[i].w * c4[i].w;
        ncp[wid][lane] = s;
    }

    // ---- main: dot(z_r, c_lane) over this wave's k-eighth ----
    float acc[BM];
    #pragma unroll
    for (int r = 0; r < BM; ++r) acc[r] = 0.f;

    const float* Zb = Z + (size_t)row0 * H + wid * 32;
    #pragma unroll
    for (int kb = 0; kb < 2; ++kb) {
        #pragma unroll
        for (int r = 0; r < BM; ++r) {
            const float4* zp = (const float4*)(Zb + r * H + kb * 16);
            float4 z0 = zp[0], z1 = zp[1], z2 = zp[2], z3 = zp[3];
            float a = acc[r];
            a += z0.x * c4[kb*4+0].x + z0.y * c4[kb*4+0].y + z0.z * c4[kb*4+0].z + z0.w * c4[kb*4+0].w;
            a += z1.x * c4[kb*4+1].x + z1.y * c4[kb*4+1].y + z1.z * c4[kb*4+1].z + z1.w * c4[kb*4+1].w;
            a += z2.x * c4[kb*4+2].x + z2.y * c4[kb*4+2].y + z2.z * c4[kb*4+2].z + z2.w * c4[kb*4+2].w;
            a += z3.x * c4[kb*4+3].x + z3.y * c4[kb*4+3].y + z3.z * c4[kb*4+3].z + z3.w * c4[kb*4+3].w;
            acc[r] = a;
        }
    }

    #pragma unroll
    for (int r = 0; r < BM; ++r) pd[wid][r][lane] = acc[r];
    __syncthreads();

    // ---- combine k-eighths, Q, row-normalize; keep Q in registers ----
    const float ncT = ncp[0][lane] + ncp[1][lane] + ncp[2][lane] + ncp[3][lane]
                    + ncp[4][lane] + ncp[5][lane] + ncp[6][lane] + ncp[7][lane];
    float qreg[2];
    float colLocal = 0.f;
    #pragma unroll
    for (int j = 0; j < 2; ++j) {
        const int r = wid * 2 + j;
        float dot = pd[0][r][lane] + pd[1][r][lane] + pd[2][r][lane] + pd[3][r][lane]
                  + pd[4][r][lane] + pd[5][r][lane] + pd[6][r][lane] + pd[7][r][lane];
        float d2  = fmaxf(nzs[r] + ncT - 2.f * dot, 0.f);
        float q   = 1.f / (1.f + sqrtf(d2));
        float s = q;
        s += __shfl_xor(s, 1);
        s += __shfl_xor(s, 2);
        s += __shfl_xor(s, 4);
        s += __shfl_xor(s, 8);
        s += __shfl_xor(s, 16);
        s += __shfl_xor(s, 32);
        float qn = q / s;
        out[(size_t)(row0 + r) * NC + lane] = qn;
        qreg[j] = qn;
        colLocal += qn;
    }
    csum[wid][lane] = colLocal;
    __syncthreads();

    // ---- publish colsum partial + arrival flag ----
    if (wid == 0)
        partials[bid * NC + lane] =
            csum[0][lane] + csum[1][lane] + csum[2][lane] + csum[3][lane] +
            csum[4][lane] + csum[5][lane] + csum[6][lane] + csum[7][lane];
    __threadfence();
    __syncthreads();
    if (t == 0)
        __hip_atomic_store(&aflag[bid], MAGIC, __ATOMIC_RELAXED, __HIP_MEMORY_SCOPE_AGENT);

    // ---- blocks 0..7: reduce one 8-cluster chunk of the colsum ----
    if (bid < 8) {
        while (__hip_atomic_load(&aflag[t], __ATOMIC_RELAXED, __HIP_MEMORY_SCOPE_AGENT) != MAGIC)
            __builtin_amdgcn_s_sleep(1);
        __threadfence();
        __syncthreads();
        const int c  = bid * 8 + (t & 7);
        const int i0 = t >> 3;               // 0..63
        float s = 0.f;
        #pragma unroll
        for (int k = 0; k < 8; ++k)
            s += partials[(i0 + 64 * k) * NC + c];
        red[t] = s;
        __syncthreads();
        if (t < 8) {
            float tot = 0.f;
            for (int i = 0; i < 64; ++i) tot += red[i * 8 + t];
            __hip_atomic_store(&invg[bid * 8 + t], 1.f / tot,
                               __ATOMIC_RELAXED, __HIP_MEMORY_SCOPE_AGENT);
        }
        __threadfence();
        __syncthreads();
        if (t == 0)
            __hip_atomic_store(&rflag[bid], MAGIC, __ATOMIC_RELAXED, __HIP_MEMORY_SCOPE_AGENT);
    }

    // ---- all blocks: wait for the 8 ready flags, fetch invcs ----
    if (t < 8)
        while (__hip_atomic_load(&rflag[t], __ATOMIC_RELAXED, __HIP_MEMORY_SCOPE_AGENT) != MAGIC)
            __builtin_amdgcn_s_sleep(2);
    __threadfence();
    __syncthreads();
    if (t < NC)
        invl[t] = __hip_atomic_load(&invg[t], __ATOMIC_RELAXED, __HIP_MEMORY_SCOPE_AGENT);
    __syncthreads();

    // ---- P from registers ----
    const float ic = invl[lane];
    #pragma unroll
    for (int j = 0; j < 2; ++j) {
        const int r = wid * 2 + j;
        float pr = qreg[j] * qreg[j] * ic;
        float s = pr;
        s += __shfl_xor(s, 1);
        s += __shfl_xor(s, 2);
        s += __shfl_xor(s, 4);
        s += __shfl_xor(s, 8);
        s += __shfl_xor(s, 16);
        s += __shfl_xor(s, 32);
        out[(size_t)(M + row0 + r) * NC + lane] = pr / s;
    }
}

extern "C" void kernel_launch(void* const* d_in, const int* in_sizes, int n_in,
                              void* d_out, int out_size, void* d_ws, size_t ws_size,
                              hipStream_t stream) {
    const float* Z = (const float*)d_in[0];   // 8192 x 256
    const float* C = (const float*)d_in[1];   // 64 x 256
    float* out = (float*)d_out;               // [Q | P]
    float* ws  = (float*)d_ws;

    k_fused<<<NBLK, 512, 0, stream>>>(Z, C, out, ws);
}

// Round 6
// 74.448 us; speedup vs baseline: 2.6681x; 2.6681x over previous
//
#include <hip/hip_runtime.h>

// ClusterNet: Q = rownorm(1/(1+dist(z,C))), P = rownorm(Q^2/colsum(Q))
// z: 8192x256 fp32, C: 64x256 fp32. out = [Q (8192x64) | P (8192x64)] fp32.
// dist^2 = ||z||^2 + ||c||^2 - 2 z.c
// Three kernels, kernel-boundary sync only (R5 showed device fences cost 100+ us).

#define M   8192
#define NC  64
#define H   256
#define BM  8      // k1 rows/block
#define NB1 1024   // k1 grid: 4 blocks/CU -> 8 waves/SIMD
#define BM2 16     // k2 rows/block

// ws layout (float index): [0, 65536) partials [1024][64]; [65536, 65600) invcs.

// ---------------- K1: distance + Q + per-block colsum partials ----------------
// 512 thr = 8 waves. lane = cluster; wave w handles k-eighth [32w, 32w+32).
// Centroid eighth in 32 VGPRs/lane; z is wave-uniform (scalar path).
__global__ __launch_bounds__(512, 8) void k1_dist_q(
    const float* __restrict__ Z, const float* __restrict__ C,
    float* __restrict__ out, float* __restrict__ ws)
{
    __shared__ float pd[8][BM][NC];   // per-wave dot partials (16 KB)
    __shared__ float ncp[8][NC];      // per-wave ||c||^2 partials
    __shared__ float nzs[BM];         // row norms
    __shared__ float csum[8][NC];     // per-wave colsum partials

    const int t    = threadIdx.x;
    const int lane = t & 63;
    const int wid  = __builtin_amdgcn_readfirstlane(t >> 6);  // wave-uniform
    const int row0 = blockIdx.x * BM;

    // ---- row norm ||z_r||^2: one wave per row, float4/lane, 64-lane reduce ----
    {
        float4 v = ((const float4*)(Z + (size_t)(row0 + wid) * H))[lane];
        float s = v.x * v.x + v.y * v.y + v.z * v.z + v.w * v.w;
        s += __shfl_xor(s, 1);
        s += __shfl_xor(s, 2);
        s += __shfl_xor(s, 4);
        s += __shfl_xor(s, 8);
        s += __shfl_xor(s, 16);
        s += __shfl_xor(s, 32);
        if (lane == 0) nzs[wid] = s;
    }

    // ---- centroid k-eighth -> 32 VGPRs (lane = cluster) ----
    float4 c4[8];
    {
        const float4* cp = (const float4*)(C + (size_t)lane * H + wid * 32);
        #pragma unroll
        for (int i = 0; i < 8; ++i) c4[i] = cp[i];
    }
    {
        float s = 0.f;
        #pragma unroll
        for (int i = 0; i < 8; ++i)
            s += c4[i].x * c4[i].x + c4[i].y * c4[i].y + c4[i].z * c4[i].z + c4[i].w * c4[i].w;
        ncp[wid][lane] = s;
    }

    // ---- main: dot(z_r, c_lane) over this wave's k-eighth ----
    float acc[BM];
    #pragma unroll
    for (int r = 0; r < BM; ++r) acc[r] = 0.f;

    const float* Zb = Z + (size_t)row0 * H + wid * 32;  // wave-uniform base
    #pragma unroll
    for (int kb = 0; kb < 2; ++kb) {
        #pragma unroll
        for (int r = 0; r < BM; ++r) {
            const float4* zp = (const float4*)(Zb + r * H + kb * 16);
            float4 z0 = zp[0], z1 = zp[1], z2 = zp[2], z3 = zp[3];
            float a = acc[r];
            a += z0.x * c4[kb*4+0].x + z0.y * c4[kb*4+0].y + z0.z * c4[kb*4+0].z + z0.w * c4[kb*4+0].w;
            a += z1.x * c4[kb*4+1].x + z1.y * c4[kb*4+1].y + z1.z * c4[kb*4+1].z + z1.w * c4[kb*4+1].w;
            a += z2.x * c4[kb*4+2].x + z2.y * c4[kb*4+2].y + z2.z * c4[kb*4+2].z + z2.w * c4[kb*4+2].w;
            a += z3.x * c4[kb*4+3].x + z3.y * c4[kb*4+3].y + z3.z * c4[kb*4+3].z + z3.w * c4[kb*4+3].w;
            acc[r] = a;
        }
    }

    #pragma unroll
    for (int r = 0; r < BM; ++r) pd[wid][r][lane] = acc[r];
    __syncthreads();

    // ---- combine k-eighths, Q, row-normalize (one row per wave) ----
    const float ncT = ncp[0][lane] + ncp[1][lane] + ncp[2][lane] + ncp[3][lane]
                    + ncp[4][lane] + ncp[5][lane] + ncp[6][lane] + ncp[7][lane];
    {
        const int r = wid;
        float dot = pd[0][r][lane] + pd[1][r][lane] + pd[2][r][lane] + pd[3][r][lane]
                  + pd[4][r][lane] + pd[5][r][lane] + pd[6][r][lane] + pd[7][r][lane];
        float d2  = fmaxf(nzs[r] + ncT - 2.f * dot, 0.f);
        float q   = 1.f / (1.f + sqrtf(d2));
        float s = q;
        s += __shfl_xor(s, 1);
        s += __shfl_xor(s, 2);
        s += __shfl_xor(s, 4);
        s += __shfl_xor(s, 8);
        s += __shfl_xor(s, 16);
        s += __shfl_xor(s, 32);
        float qn = q / s;
        out[(size_t)(row0 + r) * NC + lane] = qn;
        csum[wid][lane] = qn;
    }
    __syncthreads();
    if (wid == 0)
        ws[blockIdx.x * NC + lane] =
            csum[0][lane] + csum[1][lane] + csum[2][lane] + csum[3][lane] +
            csum[4][lane] + csum[5][lane] + csum[6][lane] + csum[7][lane];
}

// ---------------- Kmid: reduce 1024x64 partials -> invcs[64] ----------------
// 16 blocks x 256 thr; block i owns clusters 4i..4i+3.
__global__ __launch_bounds__(256, 2) void kmid_reduce(
    const float* __restrict__ ws, float* __restrict__ invcs)
{
    __shared__ float red[256];
    const int t = threadIdx.x;
    const int c = blockIdx.x * 4 + (t & 3);
    const int r0 = t >> 2;               // 0..63
    float s = 0.f;
    #pragma unroll
    for (int j = 0; j < 16; ++j)
        s += ws[(size_t)(r0 + 64 * j) * NC + c];
    red[t] = s;
    __syncthreads();
    if (t < 4) {
        float tot = 0.f;
        for (int g = 0; g < 64; ++g) tot += red[g * 4 + t];
        invcs[blockIdx.x * 4 + t] = 1.f / tot;
    }
}

// ---------------- K2: P = rownorm(Q^2 * invcs) ----------------
__global__ __launch_bounds__(256, 2) void k2_p(
    float* __restrict__ out, const float* __restrict__ invcs)
{
    const int t    = threadIdx.x;
    const int lane = t & 63;
    const int wid  = t >> 6;
    const float ic = invcs[lane];
    const int row0 = blockIdx.x * BM2;
    #pragma unroll
    for (int j = 0; j < 4; ++j) {
        const int r = row0 + wid * 4 + j;
        float q  = out[(size_t)r * NC + lane];
        float pr = q * q * ic;
        float s = pr;
        s += __shfl_xor(s, 1);
        s += __shfl_xor(s, 2);
        s += __shfl_xor(s, 4);
        s += __shfl_xor(s, 8);
        s += __shfl_xor(s, 16);
        s += __shfl_xor(s, 32);
        out[(size_t)(M + r) * NC + lane] = pr / s;
    }
}

extern "C" void kernel_launch(void* const* d_in, const int* in_sizes, int n_in,
                              void* d_out, int out_size, void* d_ws, size_t ws_size,
                              hipStream_t stream) {
    const float* Z = (const float*)d_in[0];   // 8192 x 256
    const float* C = (const float*)d_in[1];   // 64 x 256
    float* out = (float*)d_out;               // [Q | P]
    float* ws  = (float*)d_ws;                // partials [1024][64]
    float* invcs = ws + 65536;

    k1_dist_q<<<NB1, 512, 0, stream>>>(Z, C, out, ws);
    kmid_reduce<<<16, 256, 0, stream>>>(ws, invcs);
    k2_p<<<512, 256, 0, stream>>>(out, invcs);
}

// Round 7
// 73.248 us; speedup vs baseline: 2.7119x; 1.0164x over previous
//
#include <hip/hip_runtime.h>

// ClusterNet: Q = rownorm(1/(1+dist(z,C))), P = rownorm(Q^2/colsum(Q))
// z: 8192x256 fp32, C: 64x256 fp32. out = [Q (8192x64) | P (8192x64)] fp32.
// dist^2 = ||z||^2 + ||c||^2 - 2 z.c
// Structure locked by experiment: R4's two-kernel form is the best of
// {4-kernel (R1), 2-kernel (R2-R4), 1-kernel fence-sync (R5: +125us), 3-kernel (R6)}.
// This round: k2 grid 512->256 to halve its redundant partial-read traffic.

#define M   8192
#define NC  64
#define H   256
#define BM  16   // k1 rows/block; grid 512 x 512thr -> 2 blk/CU, 4 waves/SIMD
#define BM2 32   // k2 rows/block; grid 256

// ---------------- K1: distance + Q + per-block colsum partials ----------------
// 512 thr = 8 waves. lane = cluster; wave w handles k-eighth [32w, 32w+32).
// Centroid eighth in 32 VGPRs/lane; z is wave-uniform (scalar path).
__global__ __launch_bounds__(512, 4) void k1_dist_q(
    const float* __restrict__ Z, const float* __restrict__ C,
    float* __restrict__ out, float* __restrict__ ws)
{
    __shared__ float pd[8][BM][NC];   // per-wave dot partials (32 KB)
    __shared__ float ncp[8][NC];      // per-wave ||c||^2 partials
    __shared__ float nzs[BM];         // row norms
    __shared__ float csum[8][NC];     // per-wave colsum partials

    const int t    = threadIdx.x;
    const int lane = t & 63;
    const int wid  = __builtin_amdgcn_readfirstlane(t >> 6);  // wave-uniform
    const int row0 = blockIdx.x * BM;

    // ---- row norms ||z_r||^2: 32 threads per row ----
    {
        const int r  = t >> 5;       // 0..15
        const int sg = t & 31;
        const float4* zr = (const float4*)(Z + (size_t)(row0 + r) * H);
        float s = 0.f;
        #pragma unroll
        for (int i = 0; i < 2; ++i) {
            float4 v = zr[sg * 2 + i];
            s += v.x * v.x + v.y * v.y + v.z * v.z + v.w * v.w;
        }
        s += __shfl_xor(s, 1);
        s += __shfl_xor(s, 2);
        s += __shfl_xor(s, 4);
        s += __shfl_xor(s, 8);
        s += __shfl_xor(s, 16);
        if (sg == 0) nzs[r] = s;
    }

    // ---- centroid k-eighth -> 32 VGPRs (lane = cluster) ----
    float4 c4[8];
    {
        const float4* cp = (const float4*)(C + (size_t)lane * H + wid * 32);
        #pragma unroll
        for (int i = 0; i < 8; ++i) c4[i] = cp[i];
    }
    {
        float s = 0.f;
        #pragma unroll
        for (int i = 0; i < 8; ++i)
            s += c4[i].x * c4[i].x + c4[i].y * c4[i].y + c4[i].z * c4[i].z + c4[i].w * c4[i].w;
        ncp[wid][lane] = s;
    }

    // ---- main: dot(z_r, c_lane) over this wave's k-eighth ----
    float acc[BM];
    #pragma unroll
    for (int r = 0; r < BM; ++r) acc[r] = 0.f;

    const float* Zb = Z + (size_t)row0 * H + wid * 32;  // wave-uniform base
    #pragma unroll
    for (int kb = 0; kb < 2; ++kb) {
        #pragma unroll
        for (int r = 0; r < BM; ++r) {
            const float4* zp = (const float4*)(Zb + r * H + kb * 16);
            float4 z0 = zp[0], z1 = zp[1], z2 = zp[2], z3 = zp[3];
            float a = acc[r];
            a += z0.x * c4[kb*4+0].x + z0.y * c4[kb*4+0].y + z0.z * c4[kb*4+0].z + z0.w * c4[kb*4+0].w;
            a += z1.x * c4[kb*4+1].x + z1.y * c4[kb*4+1].y + z1.z * c4[kb*4+1].z + z1.w * c4[kb*4+1].w;
            a += z2.x * c4[kb*4+2].x + z2.y * c4[kb*4+2].y + z2.z * c4[kb*4+2].z + z2.w * c4[kb*4+2].w;
            a += z3.x * c4[kb*4+3].x + z3.y * c4[kb*4+3].y + z3.z * c4[kb*4+3].z + z3.w * c4[kb*4+3].w;
            acc[r] = a;
        }
    }

    #pragma unroll
    for (int r = 0; r < BM; ++r) pd[wid][r][lane] = acc[r];
    __syncthreads();

    // ---- combine k-eighths, Q, row-normalize, colsum partial ----
    const float ncT = ncp[0][lane] + ncp[1][lane] + ncp[2][lane] + ncp[3][lane]
                    + ncp[4][lane] + ncp[5][lane] + ncp[6][lane] + ncp[7][lane];
    float colLocal = 0.f;
    #pragma unroll
    for (int j = 0; j < 2; ++j) {
        const int r = wid * 2 + j;
        float dot = pd[0][r][lane] + pd[1][r][lane] + pd[2][r][lane] + pd[3][r][lane]
                  + pd[4][r][lane] + pd[5][r][lane] + pd[6][r][lane] + pd[7][r][lane];
        float d2  = fmaxf(nzs[r] + ncT - 2.f * dot, 0.f);
        float q   = 1.f / (1.f + sqrtf(d2));
        float s = q;
        s += __shfl_xor(s, 1);
        s += __shfl_xor(s, 2);
        s += __shfl_xor(s, 4);
        s += __shfl_xor(s, 8);
        s += __shfl_xor(s, 16);
        s += __shfl_xor(s, 32);
        float qn = q / s;
        out[(size_t)(row0 + r) * NC + lane] = qn;
        colLocal += qn;
    }
    csum[wid][lane] = colLocal;
    __syncthreads();
    if (wid == 0)
        ws[blockIdx.x * NC + lane] =
            csum[0][lane] + csum[1][lane] + csum[2][lane] + csum[3][lane] +
            csum[4][lane] + csum[5][lane] + csum[6][lane] + csum[7][lane];
}

// ---------------- K2: colsum reduce (redundant per block) + P ----------------
// grid 256 x 256 thr; each block reduces the 512x64 partials (128 KB, L2-hot).
__global__ __launch_bounds__(256, 2) void k2_p(
    float* __restrict__ out, const float* __restrict__ ws)
{
    __shared__ float4 red[256];
    __shared__ float invcs[NC];
    const int t  = threadIdx.x;
    const int g  = t & 15;    // cluster-quad
    const int s0 = t >> 4;    // 0..15
    const float4* w4 = (const float4*)ws;   // [512 blocks][16 float4]
    float4 a = make_float4(0.f, 0.f, 0.f, 0.f);
    #pragma unroll
    for (int i = 0; i < 32; ++i) {
        float4 v = w4[(size_t)(s0 + 16 * i) * 16 + g];
        a.x += v.x; a.y += v.y; a.z += v.z; a.w += v.w;
    }
    red[t] = a;
    __syncthreads();
    if (t < 16) {
        float4 s = red[t];
        for (int i = 1; i < 16; ++i) {
            float4 v = red[i * 16 + t];
            s.x += v.x; s.y += v.y; s.z += v.z; s.w += v.w;
        }
        invcs[4 * t + 0] = 1.f / s.x;
        invcs[4 * t + 1] = 1.f / s.y;
        invcs[4 * t + 2] = 1.f / s.z;
        invcs[4 * t + 3] = 1.f / s.w;
    }
    __syncthreads();

    const int lane = t & 63;
    const int wid  = t >> 6;
    const float ic = invcs[lane];
    const int row0 = blockIdx.x * BM2;
    #pragma unroll
    for (int j = 0; j < 8; ++j) {
        const int r = row0 + wid * 8 + j;
        float q  = out[(size_t)r * NC + lane];
        float pr = q * q * ic;
        float s = pr;
        s += __shfl_xor(s, 1);
        s += __shfl_xor(s, 2);
        s += __shfl_xor(s, 4);
        s += __shfl_xor(s, 8);
        s += __shfl_xor(s, 16);
        s += __shfl_xor(s, 32);
        out[(size_t)(M + r) * NC + lane] = pr / s;
    }
}

extern "C" void kernel_launch(void* const* d_in, const int* in_sizes, int n_in,
                              void* d_out, int out_size, void* d_ws, size_t ws_size,
                              hipStream_t stream) {
    const float* Z = (const float*)d_in[0];   // 8192 x 256
    const float* C = (const float*)d_in[1];   // 64 x 256
    float* out = (float*)d_out;               // [Q | P]
    float* ws  = (float*)d_ws;                // 512*64 colsum partials (128 KB)

    k1_dist_q<<<512, 512, 0, stream>>>(Z, C, out, ws);
    k2_p<<<256, 256, 0, stream>>>(out, ws);
}